// Round 1
// baseline (248.324 us; speedup 1.0000x reference)
//
#include <hip/hip_runtime.h>
#include <hip/hip_bf16.h>
#include <math.h>

// Problem constants (fixed by the reference): ip (8, 256, 128, 128) fp32.
#define NB   8
#define NC   256
#define NHW  (128 * 128)

// GEMM tiling
#define BM 128          // c-tile
#define BN 128          // p-tile (spatial)
#define BK 32           // k-step per iteration
#define LSTR 80         // LDS row stride in BYTES (64 B data + 16 B pad; 5 bank-quads -> conflict-free b128)

typedef __attribute__((ext_vector_type(4))) float f32x4;
typedef __attribute__((ext_vector_type(8))) short bf16x8;

// Round-to-nearest-even fp32 -> bf16 (bit trick)
__device__ __forceinline__ unsigned short f2bf(float f) {
    unsigned u = __builtin_bit_cast(unsigned, f);
    u += 0x7fffu + ((u >> 16) & 1u);
    return (unsigned short)(u >> 16);
}

// Kernel 1: DCT-III coefficient matrix, bf16, row-major [c][k], 256x256.
// M[c][k] = (k==0) ? 1 : 2*cos(pi*k*(2c+1)/512).
// Integer angle reduction: k*(2c+1) mod 1024 is exact -> cosf arg in [0, 2pi).
__global__ void coef_kernel(unsigned short* __restrict__ coef) {
    int idx = blockIdx.x * 256 + threadIdx.x;     // 0..65535
    int c = idx >> 8;
    int k = idx & 255;
    int t = (k * (2 * c + 1)) & 1023;
    float v = (k == 0) ? 1.0f : 2.0f * cosf((float)t * (float)(M_PI / 512.0));
    coef[idx] = f2bf(v);
}

// Kernel 2: per-batch GEMM Out[c,p] = sum_k M[c,k] * X[k,p]
// grid: (NHW/BN, NC/BM, NB), block: 256 threads = 4 waves (2x2 wave grid, 64x64 each)
__global__ __launch_bounds__(256, 2)
void dct_gemm(const float* __restrict__ X, const unsigned short* __restrict__ Mcoef,
              float* __restrict__ Out) {
    __shared__ unsigned char lds[2 * BM * LSTR];   // A tile (c x k), then X tile (p x k) transposed
    unsigned char* Alds = lds;
    unsigned char* Xlds = lds + BM * LSTR;

    const int tid  = threadIdx.x;
    const int lane = tid & 63;
    const int wave = tid >> 6;
    const int wm   = wave >> 1;       // 0..1 -> c-half
    const int wn   = wave & 1;        // 0..1 -> p-half
    const int m16  = lane & 15;
    const int quad = lane >> 4;

    const int p0 = blockIdx.x * BN;
    const int c0 = blockIdx.y * BM;
    const int bbase = blockIdx.z * (NC * NHW);

    const float* Xb = X + bbase;
    float* Ob = Out + bbase;

    // staging roles: row sr in [0,128), half sh selects k sub-chunk of 16
    const int sr = tid & 127;
    const int sh = tid >> 7;

    f32x4 acc[4][4];
#pragma unroll
    for (int i = 0; i < 4; i++)
#pragma unroll
        for (int j = 0; j < 4; j++) acc[i][j] = (f32x4){0.f, 0.f, 0.f, 0.f};

    for (int k0 = 0; k0 < NC; k0 += BK) {
        __syncthreads();   // previous iter's fragment reads done before overwrite

        // ---- stage A tile: rows c0+sr, cols k0+sh*16 .. +15 (32 B/thread) ----
        {
            const unsigned short* src = Mcoef + (c0 + sr) * NC + k0 + sh * 16;
            int4 a0 = *(const int4*)(src);
            int4 a1 = *(const int4*)(src + 8);
            unsigned char* dst = Alds + sr * LSTR + sh * 32;
            *(int4*)(dst)      = a0;
            *(int4*)(dst + 16) = a1;
        }

        // ---- stage X tile transposed: [p][k] bf16. thread: p = p0+sr, k = k0+sh*16..+15 ----
        {
            const float* src = Xb + (k0 + sh * 16) * NHW + p0 + sr;
            float v[16];
#pragma unroll
            for (int j = 0; j < 16; j++) v[j] = src[j * NHW];   // coalesced across lanes (p contiguous)
            unsigned pk[8];
#pragma unroll
            for (int j = 0; j < 8; j++) {
                unsigned lo = __builtin_bit_cast(unsigned, v[2 * j]);
                lo += 0x7fffu + ((lo >> 16) & 1u);
                unsigned hi = __builtin_bit_cast(unsigned, v[2 * j + 1]);
                hi += 0x7fffu + ((hi >> 16) & 1u);
                pk[j] = (lo >> 16) | (hi & 0xffff0000u);
            }
            unsigned char* dst = Xlds + sr * LSTR + sh * 32;
            *(int4*)(dst)      = (int4){(int)pk[0], (int)pk[1], (int)pk[2], (int)pk[3]};
            *(int4*)(dst + 16) = (int4){(int)pk[4], (int)pk[5], (int)pk[6], (int)pk[7]};
        }

        __syncthreads();

        // ---- fragments + MFMA ----
        bf16x8 afrag[4], bfrag[4];
#pragma unroll
        for (int mt = 0; mt < 4; mt++) {
            int row = wm * 64 + mt * 16 + m16;
            afrag[mt] = *(const bf16x8*)(Alds + row * LSTR + quad * 16);
        }
#pragma unroll
        for (int nt = 0; nt < 4; nt++) {
            int row = wn * 64 + nt * 16 + m16;
            bfrag[nt] = *(const bf16x8*)(Xlds + row * LSTR + quad * 16);
        }
#pragma unroll
        for (int mt = 0; mt < 4; mt++)
#pragma unroll
            for (int nt = 0; nt < 4; nt++)
                acc[mt][nt] = __builtin_amdgcn_mfma_f32_16x16x32_bf16(
                    afrag[mt], bfrag[nt], acc[mt][nt], 0, 0, 0);
    }

    // ---- epilogue: D layout col = lane&15 (p), row = quad*4 + r (c) ----
#pragma unroll
    for (int mt = 0; mt < 4; mt++) {
#pragma unroll
        for (int nt = 0; nt < 4; nt++) {
            int cc = c0 + wm * 64 + mt * 16 + quad * 4;
            int pp = p0 + wn * 64 + nt * 16 + m16;
            float* o = Ob + cc * NHW + pp;
#pragma unroll
            for (int r = 0; r < 4; r++)
                o[r * NHW] = acc[mt][nt][r];
        }
    }
}

extern "C" void kernel_launch(void* const* d_in, const int* in_sizes, int n_in,
                              void* d_out, int out_size, void* d_ws, size_t ws_size,
                              hipStream_t stream) {
    const float* ip = (const float*)d_in[0];
    float* out = (float*)d_out;
    unsigned short* coef = (unsigned short*)d_ws;   // 256*256*2 = 128 KB of scratch

    // must redo every launch: d_ws is re-poisoned before each timed call
    coef_kernel<<<dim3(256), dim3(256), 0, stream>>>(coef);

    dim3 grid(NHW / BN, NC / BM, NB);   // (128, 2, 8)
    dct_gemm<<<grid, dim3(256), 0, stream>>>(ip, coef, out);
}